// Round 12
// baseline (78.906 us; speedup 1.0000x reference)
//
#include <hip/hip_runtime.h>

#define HDIM 256
#define SEQ 2048
#define TPOS 32

typedef _Float16 half8_t __attribute__((ext_vector_type(8)));
typedef float floatx16 __attribute__((ext_vector_type(16)));

#define U_PITCH 1024                     // bytes per U row (256 f32)
#define H_PITCH 512                      // bytes per h/x row (256 f16)
#define U_ROWS 47                        // 32 positions + 15 halo
#define H0_OFF (U_ROWS * U_PITCH)        // 48128
#define H1_OFF (H0_OFF + 16384)         // 64512
#define LDS_BYTES (H0_OFF + 32768)       // 80896 <= 81920 -> 2 WGs/CU guaranteed

static __device__ __forceinline__ float exp2f_fast(float x) {
  float r; asm("v_exp_f32 %0, %1" : "=v"(r) : "v"(x)); return r;
}
static __device__ __forceinline__ float rcpf_fast(float x) {
  float r; asm("v_rcp_f32 %0, %1" : "=v"(r) : "v"(x)); return r;
}
// tanh(x) = 1 - 2/(exp2(2*log2e*x)+1); 3 VALU + 2 trans, saturates at +-inf.
static __device__ __forceinline__ float tanhf_fast(float x) {
  float e = exp2f_fast(x * 2.8853900817779268f);
  return 1.0f - 2.0f * rcpf_fast(e + 1.0f);
}
static __device__ __forceinline__ unsigned pkh(float a, float b) {
  return __builtin_bit_cast(unsigned, __builtin_amdgcn_cvt_pkrtz(a, b));
}

// R12: winning wave-shape (j=32, Wf=64 regs, depth-split 2 streams) in a
// 2-barrier-domain partitioning. WG = 8 waves owns ONE 32-pos tile; wave w
// covers j in [32w, 32w+32). LDS/WG = 80896 <= half of 160K -> 2 WGs/CU,
// 16 waves/CU, 4 waves/SIMD from 2 DECOUPLED barrier domains (when WG A
// drains at its barrier, WG B's waves keep the LDS/MFMA pipes fed).
// MFMA: D[j][p] = sum_k W[j][k] * h[p][k]  (A-op = W rows, B-op = h^T).
// A-frag: lane holds A[l&31][(l>>5)*8+i]; B-frag: B[(l>>5)*8+i][l&31];
// C/D:    col = l&31 (=p), row j_local = (r&3) + 8*(r>>2) + 4*(l>>5).
// NOTE: __launch_bounds__ 2nd arg = min BLOCKS/CU on this toolchain (R3).
// (512,2) -> 16 waves/CU -> 128-reg cap; demand ~120 fits (R8-proven shape).
__global__ __launch_bounds__(512, 2) void winrnn_kernel(
    const float* __restrict__ x, const float* __restrict__ W_ih,
    const float* __restrict__ W_hh, const float* __restrict__ b_ih,
    const float* __restrict__ b_hh, float* __restrict__ out) {
  extern __shared__ char smem[];
  const int tid = threadIdx.x;
  const int w = tid >> 6;
  const int lane = tid & 63;
  const int l31 = lane & 31;
  const int hi = lane >> 5;

  const int wg = blockIdx.x;
  const int batch = wg >> 6;                 // 64 tiles of 32 pos per batch row
  const int t0 = (wg & 63) * TPOS;
  const float* xb = x + (size_t)batch * SEQ * HDIM;

  const int jbase = w * 32;
  const int hswz = l31 << 4;

  // ---- stage x rows [t0-15, t0+32) as f16, swizzled, into h region ----
  {
    char* xl = smem + H0_OFF;
#pragma unroll
    for (int it = 0; it < 6; ++it) {
      int idx = tid + it * 512;              // 47 rows * 64 float4-chunks = 3008
      int row = idx >> 6;
      int c4 = idx & 63;
      int xi = t0 - 15 + row;
      if (row < U_ROWS) {
        float4 v = make_float4(0.f, 0.f, 0.f, 0.f);
        if (xi >= 0)
          v = *reinterpret_cast<const float4*>(xb + (size_t)xi * HDIM + c4 * 4);
        uint2 u;
        u.x = pkh(v.x, v.y);
        u.y = pkh(v.z, v.w);
        *reinterpret_cast<uint2*>(xl + row * H_PITCH + ((c4 * 8) ^ ((row & 31) << 4))) = u;
      }
    }
  }

  // ---- W_ih fragments (f32 -> f16), 32 j-rows per wave ----
  half8_t Wf[16];
#pragma unroll
  for (int kt = 0; kt < 16; ++kt) {
    const float* wp = W_ih + (size_t)(jbase + l31) * HDIM + kt * 16 + hi * 8;
    float4 a = *reinterpret_cast<const float4*>(wp);
    float4 b = *reinterpret_cast<const float4*>(wp + 4);
    uint4 uu;
    uu.x = pkh(a.x, a.y); uu.y = pkh(a.z, a.w);
    uu.z = pkh(b.x, b.y); uu.w = pkh(b.z, b.w);
    Wf[kt] = __builtin_bit_cast(half8_t, uu);
  }

  // ---- bias (b_ih + b_hh) in D-fragment layout ----
  float4 biasf[4];
#pragma unroll
  for (int g = 0; g < 4; ++g) {
    int j0 = jbase + g * 8 + hi * 4;
    float4 bi = *reinterpret_cast<const float4*>(b_ih + j0);
    float4 bh = *reinterpret_cast<const float4*>(b_hh + j0);
    biasf[g] = make_float4(bi.x + bh.x, bi.y + bh.y, bi.z + bh.z, bi.w + bh.w);
  }

  __syncthreads();

  // ---- U = x @ W_ih^T + bias (f32, swizzled); 2 row-tiles per wave ----
  {
    const char* xl = smem + H0_OFF;
    char* Ul = smem;
#pragma unroll
    for (int s = 0; s < 2; ++s) {
      int prow = s * 32 + l31;
      floatx16 acc;
#pragma unroll
      for (int g = 0; g < 4; ++g) {
        acc[4*g+0] = biasf[g].x; acc[4*g+1] = biasf[g].y;
        acc[4*g+2] = biasf[g].z; acc[4*g+3] = biasf[g].w;
      }
#pragma unroll
      for (int kt = 0; kt < 16; ++kt) {
        half8_t xB = *reinterpret_cast<const half8_t*>(
            xl + prow * H_PITCH + ((kt * 32 + hi * 16) ^ ((prow & 31) << 4)));
        acc = __builtin_amdgcn_mfma_f32_32x32x16_f16(Wf[kt], xB, acc, 0, 0, 0);
      }
      if (prow < U_ROWS) {
        int uswz = (prow & 31) << 4;
#pragma unroll
        for (int g = 0; g < 4; ++g) {
          int j0 = jbase + g * 8 + hi * 4;
          float4 st;
          st.x = acc[4*g+0]; st.y = acc[4*g+1]; st.z = acc[4*g+2]; st.w = acc[4*g+3];
          *reinterpret_cast<float4*>(Ul + prow * U_PITCH + ((j0 * 4) ^ uswz)) = st;
        }
      }
    }
  }

  // ---- reload Wf with W_hh (register-only) ----
#pragma unroll
  for (int kt = 0; kt < 16; ++kt) {
    const float* wp = W_hh + (size_t)(jbase + l31) * HDIM + kt * 16 + hi * 8;
    float4 a = *reinterpret_cast<const float4*>(wp);
    float4 b = *reinterpret_cast<const float4*>(wp + 4);
    uint4 uu;
    uu.x = pkh(a.x, a.y); uu.y = pkh(a.z, a.w);
    uu.z = pkh(b.x, b.y); uu.w = pkh(b.z, b.w);
    Wf[kt] = __builtin_bit_cast(half8_t, uu);
  }

  __syncthreads();

  // ---- 16-step recurrence; depth-split = 2 independent streams/wave ----
  const char* Ul = smem;
  char* hb0 = smem + H0_OFF;
  char* hb1 = smem + H1_OFF;
  floatx16 acc0, acc0b;

  for (int k = 0; k < 16; ++k) {
    // chain head: U read directly into acc (independent of the h barrier)
    {
      const int urow = l31 + k;              // 0..46
      const int uswz = (urow & 31) << 4;
#pragma unroll
      for (int g = 0; g < 4; ++g) {
        int j00 = (jbase + g * 8 + hi * 4) * 4;
        float4 u0 = *reinterpret_cast<const float4*>(Ul + urow * U_PITCH + (j00 ^ uswz));
        acc0[4*g+0] = u0.x; acc0[4*g+1] = u0.y; acc0[4*g+2] = u0.z; acc0[4*g+3] = u0.w;
        acc0b[4*g+0] = 0.f; acc0b[4*g+1] = 0.f; acc0b[4*g+2] = 0.f; acc0b[4*g+3] = 0.f;
      }
    }
    if (k > 0) {
      const char* hr = (k & 1) ? hb0 : hb1;  // buffer written by step k-1
#pragma unroll
      for (int kt = 0; kt < 8; ++kt) {
        int off0 = (kt * 32 + hi * 16) ^ hswz;
        int off1 = ((kt + 8) * 32 + hi * 16) ^ hswz;
        half8_t h0 = *reinterpret_cast<const half8_t*>(hr + l31 * H_PITCH + off0);
        half8_t h1 = *reinterpret_cast<const half8_t*>(hr + l31 * H_PITCH + off1);
        acc0  = __builtin_amdgcn_mfma_f32_32x32x16_f16(Wf[kt],     h0, acc0,  0, 0, 0);
        acc0b = __builtin_amdgcn_mfma_f32_32x32x16_f16(Wf[kt + 8], h1, acc0b, 0, 0, 0);
      }
    }
    if (k < 15) {
      char* hw = (k & 1) ? hb1 : hb0;
#pragma unroll
      for (int g = 0; g < 4; ++g) {
        float a0 = tanhf_fast(acc0[4*g+0] + acc0b[4*g+0]);
        float a1 = tanhf_fast(acc0[4*g+1] + acc0b[4*g+1]);
        float a2 = tanhf_fast(acc0[4*g+2] + acc0b[4*g+2]);
        float a3 = tanhf_fast(acc0[4*g+3] + acc0b[4*g+3]);
        int jb = (jbase + g * 8 + hi * 4) * 2;
        uint2 u0; u0.x = pkh(a0, a1); u0.y = pkh(a2, a3);
        *reinterpret_cast<uint2*>(hw + l31 * H_PITCH + (jb ^ hswz)) = u0;
      }
      __syncthreads();
    }
  }
  acc0 += acc0b;

  // ---- epilogue: final tanh -> f32 staged in LDS (h region) -> coalesced out ----
  __syncthreads();   // all step-15 h reads complete before overwrite
  {
    char* ol = smem + H0_OFF;                // 32 rows x 1024 B = 32768
    const int oswz = (l31 & 31) << 4;
#pragma unroll
    for (int g = 0; g < 4; ++g) {
      float4 st;
      st.x = tanhf_fast(acc0[4*g+0]); st.y = tanhf_fast(acc0[4*g+1]);
      st.z = tanhf_fast(acc0[4*g+2]); st.w = tanhf_fast(acc0[4*g+3]);
      int jb4 = (jbase + g * 8 + hi * 4) * 4;
      *reinterpret_cast<float4*>(ol + l31 * 1024 + (jb4 ^ oswz)) = st;
    }
  }
  __syncthreads();
  {
    const char* ol = smem + H0_OFF;
    float* ob = out + ((size_t)batch * SEQ + t0) * HDIM;
#pragma unroll
    for (int it = 0; it < 4; ++it) {
      int idx = tid + it * 512;               // 32 rows * 64 chunks
      int row = idx >> 6;
      int c = idx & 63;
      float4 v = *reinterpret_cast<const float4*>(
          ol + row * 1024 + ((c * 16) ^ ((row & 31) << 4)));
      *reinterpret_cast<float4*>(ob + (size_t)row * HDIM + c * 4) = v;
    }
  }
}

extern "C" void kernel_launch(void* const* d_in, const int* in_sizes, int n_in,
                              void* d_out, int out_size, void* d_ws, size_t ws_size,
                              hipStream_t stream) {
  const float* x    = (const float*)d_in[0];
  const float* W_ih = (const float*)d_in[1];
  const float* W_hh = (const float*)d_in[2];
  const float* b_ih = (const float*)d_in[3];
  const float* b_hh = (const float*)d_in[4];
  float* out = (float*)d_out;
  static_assert(2 * LDS_BYTES <= 160 * 1024, "need 2 WGs/CU");
  hipFuncSetAttribute(reinterpret_cast<const void*>(winrnn_kernel),
                      hipFuncAttributeMaxDynamicSharedMemorySize, LDS_BYTES);
  winrnn_kernel<<<dim3(512), dim3(512), LDS_BYTES, stream>>>(x, W_ih, W_hh, b_ih, b_hh, out);
}

// Round 13
// 78.858 us; speedup vs baseline: 1.0006x; 1.0006x over previous
//
#include <hip/hip_runtime.h>

#define HDIM 256
#define SEQ 2048

typedef _Float16 half8_t __attribute__((ext_vector_type(8)));
typedef float floatx16 __attribute__((ext_vector_type(16)));

#define U_PITCH 1024                     // bytes per U row (256 f32)
#define H_PITCH 512                      // bytes per h/x row (256 f16)
#define U_ROWS 79                        // 64 positions + 15 halo
#define HA0_OFF (U_ROWS * U_PITCH)       // 80896; h buffers: tile t, buf b at
                                         // HA0_OFF + t*32768 + b*16384
#define LDS_BYTES (HA0_OFF + 65536)      // 146432 <= 163840 -> 1 WG/CU

static __device__ __forceinline__ float exp2f_fast(float x) {
  float r; asm("v_exp_f32 %0, %1" : "=v"(r) : "v"(x)); return r;
}
static __device__ __forceinline__ float rcpf_fast(float x) {
  float r; asm("v_rcp_f32 %0, %1" : "=v"(r) : "v"(x)); return r;
}
// tanh(x) = 1 - 2/(exp2(2*log2e*x)+1); 3 VALU + 2 trans, saturates at +-inf.
static __device__ __forceinline__ float tanhf_fast(float x) {
  float e = exp2f_fast(x * 2.8853900817779268f);
  return 1.0f - 2.0f * rcpf_fast(e + 1.0f);
}
static __device__ __forceinline__ unsigned pkh(float a, float b) {
  return __builtin_bit_cast(unsigned, __builtin_amdgcn_cvt_pkrtz(a, b));
}

// R13: 16 waves/WG (1024 thr) -> 4 waves/SIMD in ONE barrier domain (the
// TLP R12 wanted without relying on 2-WG co-residency, which this toolchain
// never granted). WG owns 64 positions = 2 tiles; wave w: tile t = w&1,
// j-slice [32*(w>>1), +32). Per wave per step: 16 h-b128 (own tile only)
// + 4 U-b128 + 4 b64 writes -- half of R8's per-wave LDS issue; total
// LDS/CU/step equals R8's (~4224 cyc) but with doubled latency hiding.
// Depth-split accumulators keep 2 independent MFMA streams per wave.
// MFMA: D[j][p] = sum_k W[j][k] * h[p][k]  (A-op = W rows, B-op = h^T).
// A-frag: lane holds A[l&31][(l>>5)*8+i]; B-frag: B[(l>>5)*8+i][l&31];
// C/D:    col = l&31 (=p), row j_local = (r&3) + 8*(r>>2) + 4*(l>>5).
// NOTE: __launch_bounds__ 2nd arg = min BLOCKS/CU on this toolchain (R3).
// (1024,1) -> 16 waves/CU -> 128-reg cap; demand ~115 fits (R8-proven shape).
__global__ __launch_bounds__(1024, 1) void winrnn_kernel(
    const float* __restrict__ x, const float* __restrict__ W_ih,
    const float* __restrict__ W_hh, const float* __restrict__ b_ih,
    const float* __restrict__ b_hh, float* __restrict__ out) {
  extern __shared__ char smem[];
  const int tid = threadIdx.x;
  const int w = tid >> 6;
  const int lane = tid & 63;
  const int l31 = lane & 31;
  const int hi = lane >> 5;

  const int wg = blockIdx.x;
  const int batch = wg >> 5;                 // 32 groups of 64 pos per batch
  const int t0 = (wg & 31) * 64;
  const float* xb = x + (size_t)batch * SEQ * HDIM;

  const int t = w & 1;                       // tile (position half)
  const int jbase = (w >> 1) * 32;           // j-slice (8 slices x 2 tiles)
  const int tb = t * 32;                     // tile base row within WG
  const int hswz = l31 << 4;
  char* const hbuf = smem + HA0_OFF + t * 32768;

  // ---- stage x rows [t0-15, t0+64) as f16 (rows 79..95 zeroed), swizzled,
  //      into the h-buffer region ----
  {
    char* xl = smem + HA0_OFF;
#pragma unroll
    for (int it = 0; it < 6; ++it) {
      int idx = tid + it * 1024;             // 96 rows * 64 float4-chunks
      int row = idx >> 6;
      int c4 = idx & 63;
      int xi = t0 - 15 + row;
      float4 v = make_float4(0.f, 0.f, 0.f, 0.f);
      if (row < U_ROWS && xi >= 0)
        v = *reinterpret_cast<const float4*>(xb + (size_t)xi * HDIM + c4 * 4);
      uint2 u;
      u.x = pkh(v.x, v.y);
      u.y = pkh(v.z, v.w);
      *reinterpret_cast<uint2*>(xl + row * H_PITCH + ((c4 * 8) ^ ((row & 31) << 4))) = u;
    }
  }

  // ---- W_ih fragments (f32 -> f16), 32 j-rows per wave ----
  half8_t Wf[16];
#pragma unroll
  for (int kt = 0; kt < 16; ++kt) {
    const float* wp = W_ih + (size_t)(jbase + l31) * HDIM + kt * 16 + hi * 8;
    float4 a = *reinterpret_cast<const float4*>(wp);
    float4 b = *reinterpret_cast<const float4*>(wp + 4);
    uint4 uu;
    uu.x = pkh(a.x, a.y); uu.y = pkh(a.z, a.w);
    uu.z = pkh(b.x, b.y); uu.w = pkh(b.z, b.w);
    Wf[kt] = __builtin_bit_cast(half8_t, uu);
  }

  // ---- bias (b_ih + b_hh) in D-fragment layout ----
  float4 biasf[4];
#pragma unroll
  for (int g = 0; g < 4; ++g) {
    int j0 = jbase + g * 8 + hi * 4;
    float4 bi = *reinterpret_cast<const float4*>(b_ih + j0);
    float4 bh = *reinterpret_cast<const float4*>(b_hh + j0);
    biasf[g] = make_float4(bi.x + bh.x, bi.y + bh.y, bi.z + bh.z, bi.w + bh.w);
  }

  __syncthreads();

  // ---- U = x @ W_ih^T + bias (f32, swizzled LDS) ----
  // Row-tiles s in {0,1,2}: parity-split by tile bit (t=0 -> {0,2}, t=1 -> {1});
  // all 8 j-slices are covered within each parity group.
  {
    const char* xl = smem + HA0_OFF;
    char* Ul = smem;
    for (int s = t; s < 3; s += 2) {
      int prow = s * 32 + l31;
      floatx16 acc;
#pragma unroll
      for (int g = 0; g < 4; ++g) {
        acc[4*g+0] = biasf[g].x; acc[4*g+1] = biasf[g].y;
        acc[4*g+2] = biasf[g].z; acc[4*g+3] = biasf[g].w;
      }
#pragma unroll
      for (int kt = 0; kt < 16; ++kt) {
        half8_t xB = *reinterpret_cast<const half8_t*>(
            xl + prow * H_PITCH + ((kt * 32 + hi * 16) ^ ((prow & 31) << 4)));
        acc = __builtin_amdgcn_mfma_f32_32x32x16_f16(Wf[kt], xB, acc, 0, 0, 0);
      }
      if (prow < U_ROWS) {
        int uswz = (prow & 31) << 4;
#pragma unroll
        for (int g = 0; g < 4; ++g) {
          int j0 = jbase + g * 8 + hi * 4;
          float4 st;
          st.x = acc[4*g+0]; st.y = acc[4*g+1]; st.z = acc[4*g+2]; st.w = acc[4*g+3];
          *reinterpret_cast<float4*>(Ul + prow * U_PITCH + ((j0 * 4) ^ uswz)) = st;
        }
      }
    }
  }

  // ---- reload Wf with W_hh (register-only) ----
#pragma unroll
  for (int kt = 0; kt < 16; ++kt) {
    const float* wp = W_hh + (size_t)(jbase + l31) * HDIM + kt * 16 + hi * 8;
    float4 a = *reinterpret_cast<const float4*>(wp);
    float4 b = *reinterpret_cast<const float4*>(wp + 4);
    uint4 uu;
    uu.x = pkh(a.x, a.y); uu.y = pkh(a.z, a.w);
    uu.z = pkh(b.x, b.y); uu.w = pkh(b.z, b.w);
    Wf[kt] = __builtin_bit_cast(half8_t, uu);
  }

  __syncthreads();

  // ---- 16-step recurrence; depth-split = 2 independent streams/wave ----
  const char* Ul = smem;
  floatx16 acc0, acc0b;

  for (int k = 0; k < 16; ++k) {
    // chain head: U read directly into acc (independent of the h barrier;
    // U region is read-only during the recurrence)
    {
      const int urow = tb + l31 + k;         // 0..78
      const int uswz = (urow & 31) << 4;
#pragma unroll
      for (int g = 0; g < 4; ++g) {
        int j00 = (jbase + g * 8 + hi * 4) * 4;
        float4 u0 = *reinterpret_cast<const float4*>(Ul + urow * U_PITCH + (j00 ^ uswz));
        acc0[4*g+0] = u0.x; acc0[4*g+1] = u0.y; acc0[4*g+2] = u0.z; acc0[4*g+3] = u0.w;
        acc0b[4*g+0] = 0.f; acc0b[4*g+1] = 0.f; acc0b[4*g+2] = 0.f; acc0b[4*g+3] = 0.f;
      }
    }
    if (k > 0) {
      const char* hr = hbuf + ((k & 1) ? 0 : 16384);   // buffer written by k-1
#pragma unroll
      for (int kt = 0; kt < 8; ++kt) {
        int off0 = (kt * 32 + hi * 16) ^ hswz;
        int off1 = ((kt + 8) * 32 + hi * 16) ^ hswz;
        half8_t h0 = *reinterpret_cast<const half8_t*>(hr + l31 * H_PITCH + off0);
        half8_t h1 = *reinterpret_cast<const half8_t*>(hr + l31 * H_PITCH + off1);
        acc0  = __builtin_amdgcn_mfma_f32_32x32x16_f16(Wf[kt],     h0, acc0,  0, 0, 0);
        acc0b = __builtin_amdgcn_mfma_f32_32x32x16_f16(Wf[kt + 8], h1, acc0b, 0, 0, 0);
      }
    }
    if (k < 15) {
      char* hw = hbuf + ((k & 1) ? 16384 : 0);
#pragma unroll
      for (int g = 0; g < 4; ++g) {
        float a0 = tanhf_fast(acc0[4*g+0] + acc0b[4*g+0]);
        float a1 = tanhf_fast(acc0[4*g+1] + acc0b[4*g+1]);
        float a2 = tanhf_fast(acc0[4*g+2] + acc0b[4*g+2]);
        float a3 = tanhf_fast(acc0[4*g+3] + acc0b[4*g+3]);
        int jb = (jbase + g * 8 + hi * 4) * 2;
        uint2 u0; u0.x = pkh(a0, a1); u0.y = pkh(a2, a3);
        *reinterpret_cast<uint2*>(hw + l31 * H_PITCH + (jb ^ hswz)) = u0;
      }
      __syncthreads();
    }
  }
  acc0 += acc0b;

  // ---- epilogue: final tanh -> f32 staged in LDS (h region) -> coalesced out ----
  __syncthreads();   // all step-15 h reads complete before overwrite
  {
    char* ol = smem + HA0_OFF;               // 64 rows x 1024 B = 65536
    const int orow = tb + l31;
    const int oswz = (orow & 31) << 4;
#pragma unroll
    for (int g = 0; g < 4; ++g) {
      float4 st;
      st.x = tanhf_fast(acc0[4*g+0]); st.y = tanhf_fast(acc0[4*g+1]);
      st.z = tanhf_fast(acc0[4*g+2]); st.w = tanhf_fast(acc0[4*g+3]);
      int jb4 = (jbase + g * 8 + hi * 4) * 4;
      *reinterpret_cast<float4*>(ol + orow * 1024 + (jb4 ^ oswz)) = st;
    }
  }
  __syncthreads();
  {
    const char* ol = smem + HA0_OFF;
    float* ob = out + ((size_t)batch * SEQ + t0) * HDIM;
#pragma unroll
    for (int it = 0; it < 4; ++it) {
      int idx = tid + it * 1024;              // 64 rows * 64 chunks
      int row = idx >> 6;
      int c = idx & 63;
      float4 v = *reinterpret_cast<const float4*>(
          ol + row * 1024 + ((c * 16) ^ ((row & 31) << 4)));
      *reinterpret_cast<float4*>(ob + (size_t)row * HDIM + c * 4) = v;
    }
  }
}

extern "C" void kernel_launch(void* const* d_in, const int* in_sizes, int n_in,
                              void* d_out, int out_size, void* d_ws, size_t ws_size,
                              hipStream_t stream) {
  const float* x    = (const float*)d_in[0];
  const float* W_ih = (const float*)d_in[1];
  const float* W_hh = (const float*)d_in[2];
  const float* b_ih = (const float*)d_in[3];
  const float* b_hh = (const float*)d_in[4];
  float* out = (float*)d_out;
  static_assert(LDS_BYTES <= 160 * 1024, "LDS budget");
  hipFuncSetAttribute(reinterpret_cast<const void*>(winrnn_kernel),
                      hipFuncAttributeMaxDynamicSharedMemorySize, LDS_BYTES);
  winrnn_kernel<<<dim3(256), dim3(1024), LDS_BYTES, stream>>>(x, W_ih, W_hh, b_ih, b_hh, out);
}